// Round 3
// baseline (28046.722 us; speedup 1.0000x reference)
//
#include <hip/hip_runtime.h>
#include <math.h>

// Problem constants
#define B_  4
#define L_  2048
#define D_  1024
#define H_  16
#define HD_ 64

// ---------------------------------------------------------------------------
// GEMM: C[M,N] = A[M,K] @ W[K,N] + bias[N]     (all fp32, row-major)
// 128x128 block tile, BK=16, 256 threads, 8x8 micro-tile per thread.
// ---------------------------------------------------------------------------
#define GBM 128
#define GBN 128
#define GBK 16

__global__ __launch_bounds__(256) void gemm_bias_kernel(
    const float* __restrict__ A, const float* __restrict__ W,
    const float* __restrict__ bias, float* __restrict__ C,
    int M, int N, int K)
{
    __shared__ __align__(16) float As[GBK][GBM + 4];  // transposed A tile
    __shared__ __align__(16) float Bs[GBK][GBN + 4];

    const int tid = threadIdx.x;
    const int m0 = blockIdx.y * GBM;
    const int n0 = blockIdx.x * GBN;
    const int tx = tid & 15;
    const int ty = tid >> 4;

    float acc[8][8];
    #pragma unroll
    for (int i = 0; i < 8; ++i)
        #pragma unroll
        for (int j = 0; j < 8; ++j) acc[i][j] = 0.f;

    const int ar0 = tid >> 2;                const int as0 = (tid & 3) << 2;
    const int ar1 = (tid + 256) >> 2;        const int as1 = as0;
    const int br0 = tid >> 5;                const int bc0 = (tid & 31) << 2;
    const int br1 = (tid + 256) >> 5;        const int bc1 = bc0;

    for (int k0 = 0; k0 < K; k0 += GBK) {
        float4 a0 = *(const float4*)&A[(size_t)(m0 + ar0) * K + k0 + as0];
        float4 a1 = *(const float4*)&A[(size_t)(m0 + ar1) * K + k0 + as1];
        float4 b0 = *(const float4*)&W[(size_t)(k0 + br0) * N + n0 + bc0];
        float4 b1 = *(const float4*)&W[(size_t)(k0 + br1) * N + n0 + bc1];

        __syncthreads();
        As[as0 + 0][ar0] = a0.x; As[as0 + 1][ar0] = a0.y;
        As[as0 + 2][ar0] = a0.z; As[as0 + 3][ar0] = a0.w;
        As[as1 + 0][ar1] = a1.x; As[as1 + 1][ar1] = a1.y;
        As[as1 + 2][ar1] = a1.z; As[as1 + 3][ar1] = a1.w;
        *(float4*)&Bs[br0][bc0] = b0;
        *(float4*)&Bs[br1][bc1] = b1;
        __syncthreads();

        #pragma unroll
        for (int kk = 0; kk < GBK; ++kk) {
            float av[8], bv[8];
            *(float4*)&av[0] = *(const float4*)&As[kk][ty * 8];
            *(float4*)&av[4] = *(const float4*)&As[kk][ty * 8 + 4];
            *(float4*)&bv[0] = *(const float4*)&Bs[kk][tx * 8];
            *(float4*)&bv[4] = *(const float4*)&Bs[kk][tx * 8 + 4];
            #pragma unroll
            for (int i = 0; i < 8; ++i)
                #pragma unroll
                for (int j = 0; j < 8; ++j)
                    acc[i][j] = fmaf(av[i], bv[j], acc[i][j]);
        }
    }

    #pragma unroll
    for (int i = 0; i < 8; ++i) {
        const size_t row = (size_t)(m0 + ty * 8 + i) * N + n0 + tx * 8;
        float4 o0, o1;
        o0.x = acc[i][0] + bias[n0 + tx * 8 + 0];
        o0.y = acc[i][1] + bias[n0 + tx * 8 + 1];
        o0.z = acc[i][2] + bias[n0 + tx * 8 + 2];
        o0.w = acc[i][3] + bias[n0 + tx * 8 + 3];
        o1.x = acc[i][4] + bias[n0 + tx * 8 + 4];
        o1.y = acc[i][5] + bias[n0 + tx * 8 + 5];
        o1.z = acc[i][6] + bias[n0 + tx * 8 + 6];
        o1.w = acc[i][7] + bias[n0 + tx * 8 + 7];
        *(float4*)&C[row]     = o0;
        *(float4*)&C[row + 4] = o1;
    }
}

// ---------------------------------------------------------------------------
// Pack mask ints -> bitmask. mbits[(b*L + q)*64 + k/32] bit (k%32).
// ---------------------------------------------------------------------------
__global__ __launch_bounds__(256) void pack_mask_kernel(
    const int* __restrict__ mask, unsigned int* __restrict__ mbits)
{
    const int g = blockIdx.x * 256 + threadIdx.x;
    const int v = mask[g];
    const unsigned long long bm = __ballot(v != 0);
    const int lane = threadIdx.x & 63;
    if (lane == 0)       mbits[g >> 5] = (unsigned int)bm;
    else if (lane == 32) mbits[g >> 5] = (unsigned int)(bm >> 32);
}

// ---------------------------------------------------------------------------
// Flash attention v3 (fp32), in-block split-K for occupancy.
// Block = 512 threads (8 waves). Threads 0-255: queries q0..q0+255 over keys
// [0, L/2); threads 256-511: same queries over keys [L/2, L). Each half
// stages its own 64x64 K/V tile (2x16KB K + 2x16KB V in one 64KB buffer).
// Final merge: upper half publishes (m,l,o) via LDS overlay, lower half
// combines (online-softmax merge) and writes ctx.
// Q,K,V,ctx layout: [B, L, H*HD].
// ---------------------------------------------------------------------------
#define BQ  256
#define BKT 64

__device__ static inline void async_copy16(const void* g, void* lds)
{
    __builtin_amdgcn_global_load_lds(
        (const __attribute__((address_space(1))) void*)g,
        (__attribute__((address_space(3))) void*)lds, 16, 0, 0);
}

#define OSTR 68   // combine-overlay row stride in floats (16B aligned, 8-way max)

__global__ __launch_bounds__(512, 4) void attn_kernel(
    const float* __restrict__ Q, const float* __restrict__ K,
    const float* __restrict__ V, const unsigned int* __restrict__ mbits,
    float* __restrict__ ctx)
{
    // [0,32KB): K tiles (half*16KB), [32KB,64KB): V tiles (half*16KB)
    __shared__ __align__(16) char smem[65536];
    __shared__ float Ml[BQ], Ll[BQ];

    const int tid  = threadIdx.x;
    const int half = tid >> 8;           // key-split id: 0 or 1
    const int qt   = tid & 255;          // query slot within block
    const int lane = tid & 63;
    const int w4   = (tid >> 6) & 3;     // wave id within half-group
    const int q0   = blockIdx.x * BQ;
    const int h    = blockIdx.y;
    const int b    = blockIdx.z;
    const int q    = q0 + qt;

    float* Kt = (float*)(smem)          + half * 4096;   // 64x64 tile
    float* Vt = (float*)(smem + 32768)  + half * 4096;

    const size_t qrow = ((size_t)(b * L_ + q)) * D_ + h * HD_;
    float4 qv4[16];
    #pragma unroll
    for (int d4 = 0; d4 < 16; ++d4)
        qv4[d4] = *(const float4*)&Q[qrow + d4 * 4];

    float4 o4[16];
    #pragma unroll
    for (int d4 = 0; d4 < 16; ++d4) o4[d4] = make_float4(0.f, 0.f, 0.f, 0.f);
    float mrun = -INFINITY, lrun = 0.f;

    // 1/sqrt(64) * log2(e): softmax in exp2 domain
    const float scale = 0.125f * 1.44269504088896340736f;

    const int kbase = half * (L_ / 2);
    const unsigned int* mrow = mbits + ((size_t)(b * L_ + q)) * (L_ / 32)
                             + (kbase >> 5);

    for (int kt = 0; kt < (L_ / 2) / BKT; ++kt) {
        const int k0 = kbase + kt * BKT;
        __syncthreads();   // previous tile's LDS reads complete (all 8 waves)
        // stage this half's K/V tile: 1024 float4 each over 256 threads
        #pragma unroll
        for (int i = 0; i < 4; ++i) {
            const int fb = i * 256 + w4 * 64;         // wave-uniform float4 base
            const int f  = fb + lane;
            const int r  = f >> 4;
            const int c4 = (f & 15) << 2;
            const size_t g = ((size_t)(b * L_ + k0 + r)) * D_ + h * HD_ + c4;
            async_copy16(&K[g], (char*)Kt + fb * 16);
            async_copy16(&V[g], (char*)Vt + fb * 16);
        }
        const uint2 mw = *(const uint2*)&mrow[kt * 2];
        const unsigned long long mb =
            ((unsigned long long)mw.y << 32) | (unsigned long long)mw.x;
        __syncthreads();   // drains vmcnt: LDS tile ready

        for (int c = 0; c < 8; ++c) {              // 8 chunks of 8 keys
            const int jb = c * 8;
            float s[8];
            #pragma unroll
            for (int jj = 0; jj < 8; ++jj) s[jj] = 0.f;

            #pragma unroll
            for (int d4 = 0; d4 < 16; ++d4) {
                const float4 qq = qv4[d4];
                #pragma unroll
                for (int jj = 0; jj < 8; ++jj) {
                    const float4 kk = *(const float4*)&Kt[(jb + jj) * 64 + d4 * 4];
                    s[jj] = fmaf(qq.x, kk.x, s[jj]);
                    s[jj] = fmaf(qq.y, kk.y, s[jj]);
                    s[jj] = fmaf(qq.z, kk.z, s[jj]);
                    s[jj] = fmaf(qq.w, kk.w, s[jj]);
                }
            }

            float cmax = -INFINITY;
            #pragma unroll
            for (int jj = 0; jj < 8; ++jj) {
                const bool on = (mb >> (jb + jj)) & 1ull;
                s[jj] = on ? s[jj] * scale : -INFINITY;
                cmax = fmaxf(cmax, s[jj]);
            }

            const float mnew  = fmaxf(mrun, cmax);
            const float msafe = fmaxf(mnew, -1e30f);
            const float alpha = exp2f(mrun - msafe);
            float pr[8], psum = 0.f;
            #pragma unroll
            for (int jj = 0; jj < 8; ++jj) {
                pr[jj] = exp2f(s[jj] - msafe);
                psum += pr[jj];
            }
            lrun = lrun * alpha + psum;
            mrun = mnew;

            #pragma unroll
            for (int d4 = 0; d4 < 16; ++d4) {
                float4 ov = o4[d4];
                ov.x *= alpha; ov.y *= alpha; ov.z *= alpha; ov.w *= alpha;
                #pragma unroll
                for (int jj = 0; jj < 8; ++jj) {
                    const float4 vv = *(const float4*)&Vt[(jb + jj) * 64 + d4 * 4];
                    ov.x = fmaf(pr[jj], vv.x, ov.x);
                    ov.y = fmaf(pr[jj], vv.y, ov.y);
                    ov.z = fmaf(pr[jj], vv.z, ov.z);
                    ov.w = fmaf(pr[jj], vv.w, ov.w);
                }
                o4[d4] = ov;
            }
        }
    }

    // -------- combine the two key-splits (upper publishes, lower merges) ----
    __syncthreads();                   // all k-loop LDS reads done
    if (half == 1) { Ml[qt] = mrun; Ll[qt] = lrun; }

    float* oex = (float*)smem;         // overlay: 128 rows x OSTR floats
    #pragma unroll 1
    for (int r = 0; r < 2; ++r) {
        __syncthreads();
        if (half == 1 && ((qt >> 7) == r)) {
            const int row = qt & 127;
            #pragma unroll
            for (int d4 = 0; d4 < 16; ++d4)
                *(float4*)&oex[row * OSTR + d4 * 4] = o4[d4];
        }
        __syncthreads();
        if (half == 0 && ((qt >> 7) == r)) {
            const int row = qt & 127;
            const float m1 = Ml[qt], l1 = Ll[qt];
            const float mnew  = fmaxf(mrun, m1);
            const float msafe = fmaxf(mnew, -1e30f);
            const float s0 = exp2f(mrun - msafe);
            const float s1 = exp2f(m1 - msafe);
            const float l  = lrun * s0 + l1 * s1;
            const float rinv = (l > 0.f) ? (1.f / l) : 0.f;
            float* outp = ctx + qrow;
            #pragma unroll
            for (int d4 = 0; d4 < 16; ++d4) {
                const float4 o1v = *(const float4*)&oex[row * OSTR + d4 * 4];
                float4 ov = o4[d4];
                ov.x = (ov.x * s0 + o1v.x * s1) * rinv;
                ov.y = (ov.y * s0 + o1v.y * s1) * rinv;
                ov.z = (ov.z * s0 + o1v.z * s1) * rinv;
                ov.w = (ov.w * s0 + o1v.w * s1) * rinv;
                *(float4*)&outp[d4 * 4] = ov;
            }
        }
    }
}

// ---------------------------------------------------------------------------
extern "C" void kernel_launch(void* const* d_in, const int* in_sizes, int n_in,
                              void* d_out, int out_size, void* d_ws, size_t ws_size,
                              hipStream_t stream)
{
    const float* q    = (const float*)d_in[0];
    const float* k    = (const float*)d_in[1];
    const float* v    = (const float*)d_in[2];
    const int*   mask = (const int*)d_in[3];
    const float* WQ   = (const float*)d_in[4];
    const float* bQ   = (const float*)d_in[5];
    const float* WK   = (const float*)d_in[6];
    const float* bK   = (const float*)d_in[7];
    const float* WV   = (const float*)d_in[8];
    const float* bV   = (const float*)d_in[9];
    const float* WO   = (const float*)d_in[10];
    const float* bO   = (const float*)d_in[11];
    float* out = (float*)d_out;

    const size_t NTOK = (size_t)B_ * L_;        // 8192 rows
    const size_t SZ   = NTOK * D_;              // 8M floats = 32 MiB
    float* Qp = (float*)d_ws;
    float* Kp = Qp + SZ;
    float* Vp = Kp + SZ;
    float* Cp = Vp + SZ;                        // 128 MiB

    const size_t MBW = (size_t)B_ * L_ * (L_ / 32);   // bitmask words
    unsigned int* mbits;
    if (ws_size >= 4 * SZ * sizeof(float) + MBW * sizeof(unsigned int))
        mbits = (unsigned int*)(Cp + SZ);
    else
        mbits = (unsigned int*)d_out;   // overwritten by final GEMM afterwards

    pack_mask_kernel<<<(B_ * L_ * L_) / 256, 256, 0, stream>>>(mask, mbits);

    dim3 gblk(256);
    dim3 ggrd(D_ / GBN, NTOK / GBM);            // (8, 64)
    gemm_bias_kernel<<<ggrd, gblk, 0, stream>>>(q, WQ, bQ, Qp, (int)NTOK, D_, D_);
    gemm_bias_kernel<<<ggrd, gblk, 0, stream>>>(k, WK, bK, Kp, (int)NTOK, D_, D_);
    gemm_bias_kernel<<<ggrd, gblk, 0, stream>>>(v, WV, bV, Vp, (int)NTOK, D_, D_);

    dim3 agrd(L_ / BQ, H_, B_);                 // (8, 16, 4)
    attn_kernel<<<agrd, dim3(512), 0, stream>>>(Qp, Kp, Vp, mbits, Cp);

    gemm_bias_kernel<<<ggrd, gblk, 0, stream>>>(Cp, WO, bO, out, (int)NTOK, D_, D_);
}

// Round 4
// 1573.374 us; speedup vs baseline: 17.8258x; 17.8258x over previous
//
#include <hip/hip_runtime.h>
#include <math.h>

// Problem constants
#define B_  4
#define L_  2048
#define D_  1024
#define H_  16
#define HD_ 64

typedef __attribute__((ext_vector_type(8))) short short8;
typedef __attribute__((ext_vector_type(4))) float f32x4;

// fp32 -> bf16 bits, round-to-nearest-even
__device__ static inline unsigned short f2bf(float f) {
    union { float f; unsigned int u; } v; v.f = f;
    const unsigned int u = v.u;
    return (unsigned short)((u + 0x7FFFu + ((u >> 16) & 1u)) >> 16);
}

__device__ static inline void async_copy16(const void* g, void* lds)
{
    __builtin_amdgcn_global_load_lds(
        (const __attribute__((address_space(1))) void*)g,
        (__attribute__((address_space(3))) void*)lds, 16, 0, 0);
}

// ---------------------------------------------------------------------------
// fp32 -> bf16 convert, 8 elements per thread
// ---------------------------------------------------------------------------
__global__ __launch_bounds__(256) void cvt_bf16_kernel(
    const float* __restrict__ in, unsigned short* __restrict__ out)
{
    const size_t i = ((size_t)blockIdx.x * 256 + threadIdx.x) * 8;
    const float4 x = *(const float4*)&in[i];
    const float4 y = *(const float4*)&in[i + 4];
    ushort4 o0, o1;
    o0.x = f2bf(x.x); o0.y = f2bf(x.y); o0.z = f2bf(x.z); o0.w = f2bf(x.w);
    o1.x = f2bf(y.x); o1.y = f2bf(y.y); o1.z = f2bf(y.z); o1.w = f2bf(y.w);
    *(ushort4*)&out[i]     = o0;
    *(ushort4*)&out[i + 4] = o1;
}

// ---------------------------------------------------------------------------
// Transpose + convert: WT[n][k] = bf16(W[k][n]), square N=1024
// ---------------------------------------------------------------------------
__global__ __launch_bounds__(256) void transpose_bf16_kernel(
    const float* __restrict__ W, unsigned short* __restrict__ WT)
{
    __shared__ float t[32][33];
    const int c  = threadIdx.x & 31;
    const int r8 = threadIdx.x >> 5;          // 0..7
    const int k0 = blockIdx.y * 32;
    const int n0 = blockIdx.x * 32;
    #pragma unroll
    for (int i = 0; i < 4; ++i) {
        const int r = r8 + i * 8;
        t[r][c] = W[(size_t)(k0 + r) * 1024 + n0 + c];
    }
    __syncthreads();
    #pragma unroll
    for (int i = 0; i < 4; ++i) {
        const int r = r8 + i * 8;
        WT[(size_t)(n0 + r) * 1024 + k0 + c] = f2bf(t[c][r]);
    }
}

// ---------------------------------------------------------------------------
// Pack mask ints -> bitmask. mbits[(b*L + q)*64 + k/32] bit (k%32).
// ---------------------------------------------------------------------------
__global__ __launch_bounds__(256) void pack_mask_kernel(
    const int* __restrict__ mask, unsigned int* __restrict__ mbits)
{
    const int g = blockIdx.x * 256 + threadIdx.x;
    const int v = mask[g];
    const unsigned long long bm = __ballot(v != 0);
    const int lane = threadIdx.x & 63;
    if (lane == 0)       mbits[g >> 5] = (unsigned int)bm;
    else if (lane == 32) mbits[g >> 5] = (unsigned int)(bm >> 32);
}

// ---------------------------------------------------------------------------
// bf16 MFMA GEMM (m97 recipe): C[M,N] = A[M,K] @ WT[N,K]^T + bias[N]
// A, WT bf16; C fp32. 128x128 block tile, BK=64, 256 threads (2x2 waves,
// 64x64 per wave via 4x4 mfma_f32_16x16x32_bf16). global_load_lds staging.
// Fragment maps (HW-verified m89/m91/m120): A/B [idx=lane&15][k=quad*8+j],
// C/D row=quad*4+reg, col=lane&15.
// ---------------------------------------------------------------------------
__global__ __launch_bounds__(256) void gemm_mfma_kernel(
    const unsigned short* __restrict__ A, const unsigned short* __restrict__ WT,
    const float* __restrict__ bias, float* __restrict__ C,
    int M, int N, int K)
{
    __shared__ __align__(16) unsigned short At[128 * 64];  // [m][k] 16 KB
    __shared__ __align__(16) unsigned short Bt[128 * 64];  // [n][k] 16 KB

    const int tid  = threadIdx.x;
    const int lane = tid & 63;
    const int wave = tid >> 6;
    const int wm   = wave >> 1;        // 0..1
    const int wn   = wave & 1;         // 0..1
    const int quad = lane >> 4;        // 0..3
    const int l15  = lane & 15;
    const int m0   = blockIdx.y * 128;
    const int n0   = blockIdx.x * 128;

    f32x4 acc[4][4];
    #pragma unroll
    for (int i = 0; i < 4; ++i)
        #pragma unroll
        for (int j = 0; j < 4; ++j) acc[i][j] = (f32x4)0.f;

    for (int k0 = 0; k0 < K; k0 += 64) {
        __syncthreads();
        // stage A and WT tiles: 1024 16B-chunks each over 256 threads
        #pragma unroll
        for (int i = 0; i < 4; ++i) {
            const int fb  = i * 256 + wave * 64;   // wave-uniform chunk base
            const int f   = fb + lane;
            const int row = f >> 3;                // 0..127
            const int c8  = f & 7;                 // 8 bf16 per chunk
            async_copy16(&A [(size_t)(m0 + row) * K + k0 + c8 * 8],
                         (char*)At + (size_t)fb * 16);
            async_copy16(&WT[(size_t)(n0 + row) * K + k0 + c8 * 8],
                         (char*)Bt + (size_t)fb * 16);
        }
        __syncthreads();

        #pragma unroll
        for (int kk = 0; kk < 64; kk += 32) {
            short8 afr[4], bfr[4];
            #pragma unroll
            for (int mt = 0; mt < 4; ++mt)
                afr[mt] = *(const short8*)&At[(size_t)(wm * 64 + mt * 16 + l15) * 64 + kk + quad * 8];
            #pragma unroll
            for (int nt = 0; nt < 4; ++nt)
                bfr[nt] = *(const short8*)&Bt[(size_t)(wn * 64 + nt * 16 + l15) * 64 + kk + quad * 8];
            #pragma unroll
            for (int mt = 0; mt < 4; ++mt)
                #pragma unroll
                for (int nt = 0; nt < 4; ++nt)
                    acc[mt][nt] = __builtin_amdgcn_mfma_f32_16x16x32_bf16(
                        afr[mt], bfr[nt], acc[mt][nt], 0, 0, 0);
        }
    }

    // epilogue: bias + store fp32
    #pragma unroll
    for (int nt = 0; nt < 4; ++nt) {
        const int col = n0 + wn * 64 + nt * 16 + l15;
        const float bv = bias[col];
        #pragma unroll
        for (int mt = 0; mt < 4; ++mt) {
            const int r0 = m0 + wm * 64 + mt * 16 + quad * 4;
            #pragma unroll
            for (int r = 0; r < 4; ++r)
                C[(size_t)(r0 + r) * N + col] = acc[mt][nt][r] + bv;
        }
    }
}

// ---------------------------------------------------------------------------
// Flash attention (fp32) — identical to R2's verified 1450us kernel.
// Block = 256 threads, one query row per thread, K/V 64x64 LDS tiles.
// ---------------------------------------------------------------------------
#define BQ  256
#define BKT 64

__global__ __launch_bounds__(256, 2) void attn_kernel(
    const float* __restrict__ Q, const float* __restrict__ K,
    const float* __restrict__ V, const unsigned int* __restrict__ mbits,
    float* __restrict__ ctx)
{
    __shared__ __align__(16) float Ks[BKT][HD_];
    __shared__ __align__(16) float Vs[BKT][HD_];

    const int tid  = threadIdx.x;
    const int lane = tid & 63;
    const int wv   = tid >> 6;
    const int q0   = blockIdx.x * BQ;
    const int h    = blockIdx.y;
    const int b    = blockIdx.z;
    const int q    = q0 + tid;

    const size_t qrow = ((size_t)(b * L_ + q)) * D_ + h * HD_;
    float4 qv4[16];
    #pragma unroll
    for (int d4 = 0; d4 < 16; ++d4)
        qv4[d4] = *(const float4*)&Q[qrow + d4 * 4];

    float4 o4[16];
    #pragma unroll
    for (int d4 = 0; d4 < 16; ++d4) o4[d4] = make_float4(0.f, 0.f, 0.f, 0.f);
    float mrun = -INFINITY, lrun = 0.f;

    const float scale = 0.125f * 1.44269504088896340736f;

    const unsigned int* mrow = mbits + ((size_t)(b * L_ + q)) * (L_ / 32);

    for (int kt = 0; kt < L_ / BKT; ++kt) {
        const int k0 = kt * BKT;
        __syncthreads();
        #pragma unroll
        for (int i = 0; i < 4; ++i) {
            const int fb = i * 256 + wv * 64;
            const int f  = fb + lane;
            const int r  = f >> 4;
            const int c4 = (f & 15) << 2;
            const size_t g = ((size_t)(b * L_ + k0 + r)) * D_ + h * HD_ + c4;
            async_copy16(&K[g], (char*)&Ks[0][0] + fb * 16);
            async_copy16(&V[g], (char*)&Vs[0][0] + fb * 16);
        }
        const uint2 mw = *(const uint2*)&mrow[kt * 2];
        const unsigned long long mb =
            ((unsigned long long)mw.y << 32) | (unsigned long long)mw.x;
        __syncthreads();

        for (int c = 0; c < 8; ++c) {
            const int jb = c * 8;
            float s[8];
            #pragma unroll
            for (int jj = 0; jj < 8; ++jj) s[jj] = 0.f;

            #pragma unroll
            for (int d4 = 0; d4 < 16; ++d4) {
                const float4 qq = qv4[d4];
                #pragma unroll
                for (int jj = 0; jj < 8; ++jj) {
                    const float4 kk = *(const float4*)&Ks[jb + jj][d4 * 4];
                    s[jj] = fmaf(qq.x, kk.x, s[jj]);
                    s[jj] = fmaf(qq.y, kk.y, s[jj]);
                    s[jj] = fmaf(qq.z, kk.z, s[jj]);
                    s[jj] = fmaf(qq.w, kk.w, s[jj]);
                }
            }

            float cmax = -INFINITY;
            #pragma unroll
            for (int jj = 0; jj < 8; ++jj) {
                const bool on = (mb >> (jb + jj)) & 1ull;
                s[jj] = on ? s[jj] * scale : -INFINITY;
                cmax = fmaxf(cmax, s[jj]);
            }

            const float mnew  = fmaxf(mrun, cmax);
            const float msafe = fmaxf(mnew, -1e30f);
            const float alpha = exp2f(mrun - msafe);
            float pr[8], psum = 0.f;
            #pragma unroll
            for (int jj = 0; jj < 8; ++jj) {
                pr[jj] = exp2f(s[jj] - msafe);
                psum += pr[jj];
            }
            lrun = lrun * alpha + psum;
            mrun = mnew;

            #pragma unroll
            for (int d4 = 0; d4 < 16; ++d4) {
                float4 ov = o4[d4];
                ov.x *= alpha; ov.y *= alpha; ov.z *= alpha; ov.w *= alpha;
                #pragma unroll
                for (int jj = 0; jj < 8; ++jj) {
                    const float4 vv = *(const float4*)&Vs[jb + jj][d4 * 4];
                    ov.x = fmaf(pr[jj], vv.x, ov.x);
                    ov.y = fmaf(pr[jj], vv.y, ov.y);
                    ov.z = fmaf(pr[jj], vv.z, ov.z);
                    ov.w = fmaf(pr[jj], vv.w, ov.w);
                }
                o4[d4] = ov;
            }
        }
    }

    const float rinv = (lrun > 0.f) ? (1.f / lrun) : 0.f;
    float* outp = ctx + qrow;
    #pragma unroll
    for (int d4 = 0; d4 < 16; ++d4) {
        float4 ov = o4[d4];
        ov.x *= rinv; ov.y *= rinv; ov.z *= rinv; ov.w *= rinv;
        *(float4*)&outp[d4 * 4] = ov;
    }
}

// ---------------------------------------------------------------------------
extern "C" void kernel_launch(void* const* d_in, const int* in_sizes, int n_in,
                              void* d_out, int out_size, void* d_ws, size_t ws_size,
                              hipStream_t stream)
{
    const float* q    = (const float*)d_in[0];
    const float* k    = (const float*)d_in[1];
    const float* v    = (const float*)d_in[2];
    const int*   mask = (const int*)d_in[3];
    const float* WQ   = (const float*)d_in[4];
    const float* bQ   = (const float*)d_in[5];
    const float* WK   = (const float*)d_in[6];
    const float* bK   = (const float*)d_in[7];
    const float* WV   = (const float*)d_in[8];
    const float* bV   = (const float*)d_in[9];
    const float* WO   = (const float*)d_in[10];
    const float* bO   = (const float*)d_in[11];
    float* out = (float*)d_out;

    const size_t NTOK = (size_t)B_ * L_;        // 8192
    const size_t SZ   = NTOK * D_;              // 8.39M elements

    // ws layout (proven >=128 MiB by R2): Qp/Kp/Vp fp32, Z zone multi-use
    float* Qp = (float*)d_ws;
    float* Kp = Qp + SZ;
    float* Vp = Kp + SZ;
    float* Zf = Vp + SZ;                        // Z zone, 32 MiB
    // Z pre-attn: qb, vb (bf16, 16 MiB each = exactly 32 MiB)
    unsigned short* qb = (unsigned short*)Zf;
    unsigned short* vb = qb + SZ;
    float* Cp = Zf;                             // Z post-attn: ctx fp32

    // d_out as scratch until final GEMM:
    //   [0,2MB) mbits, [2,8MB) WTq/WTk/WTv, [8,25MB) kb
    unsigned int*   mbits = (unsigned int*)d_out;
    unsigned short* WTq = (unsigned short*)((char*)d_out + (2  << 20));
    unsigned short* WTk = (unsigned short*)((char*)d_out + (4  << 20));
    unsigned short* WTv = (unsigned short*)((char*)d_out + (6  << 20));
    unsigned short* kb  = (unsigned short*)((char*)d_out + (8  << 20));
    // post-attn: WTo in dead Kp zone, cb in dead Qp zone
    unsigned short* WTo = (unsigned short*)Kp;
    unsigned short* cb  = (unsigned short*)Qp;

    pack_mask_kernel<<<(B_ * L_ * L_) / 256, 256, 0, stream>>>(mask, mbits);

    const int cvtg = (int)(SZ / (256 * 8));     // 4096 blocks
    cvt_bf16_kernel<<<cvtg, 256, 0, stream>>>(q, qb);
    cvt_bf16_kernel<<<cvtg, 256, 0, stream>>>(k, kb);
    cvt_bf16_kernel<<<cvtg, 256, 0, stream>>>(v, vb);

    dim3 tg(32, 32);
    transpose_bf16_kernel<<<tg, 256, 0, stream>>>(WQ, WTq);
    transpose_bf16_kernel<<<tg, 256, 0, stream>>>(WK, WTk);
    transpose_bf16_kernel<<<tg, 256, 0, stream>>>(WV, WTv);

    dim3 ggrd(D_ / 128, NTOK / 128);            // (8, 64)
    gemm_mfma_kernel<<<ggrd, 256, 0, stream>>>(qb, WTq, bQ, Qp, (int)NTOK, D_, D_);
    gemm_mfma_kernel<<<ggrd, 256, 0, stream>>>(kb, WTk, bK, Kp, (int)NTOK, D_, D_);
    gemm_mfma_kernel<<<ggrd, 256, 0, stream>>>(vb, WTv, bV, Vp, (int)NTOK, D_, D_);

    dim3 agrd(L_ / BQ, H_, B_);                 // (8, 16, 4)
    attn_kernel<<<agrd, dim3(256), 0, stream>>>(Qp, Kp, Vp, mbits, Cp);

    // Kp/Qp dead now; stage O-projection operands there
    transpose_bf16_kernel<<<tg, 256, 0, stream>>>(WO, WTo);
    cvt_bf16_kernel<<<cvtg, 256, 0, stream>>>(Cp, cb);

    gemm_mfma_kernel<<<ggrd, 256, 0, stream>>>(cb, WTo, bO, out, (int)NTOK, D_, D_);
}

// Round 5
// 574.065 us; speedup vs baseline: 48.8564x; 2.7408x over previous
//
#include <hip/hip_runtime.h>
#include <math.h>

// Problem constants
#define B_  4
#define L_  2048
#define D_  1024
#define H_  16
#define HD_ 64

typedef __attribute__((ext_vector_type(8))) short short8;
typedef __attribute__((ext_vector_type(4))) float f32x4;

// fp32 -> bf16 bits, round-to-nearest-even
__device__ static inline unsigned short f2bf(float f) {
    union { float f; unsigned int u; } v; v.f = f;
    const unsigned int u = v.u;
    return (unsigned short)((u + 0x7FFFu + ((u >> 16) & 1u)) >> 16);
}

__device__ static inline void async_copy16(const void* g, void* lds)
{
    __builtin_amdgcn_global_load_lds(
        (const __attribute__((address_space(1))) void*)g,
        (__attribute__((address_space(3))) void*)lds, 16, 0, 0);
}

// ---------------------------------------------------------------------------
// fp32 -> bf16 convert, 8 elements per thread
// ---------------------------------------------------------------------------
__global__ __launch_bounds__(256) void cvt_bf16_kernel(
    const float* __restrict__ in, unsigned short* __restrict__ out)
{
    const size_t i = ((size_t)blockIdx.x * 256 + threadIdx.x) * 8;
    const float4 x = *(const float4*)&in[i];
    const float4 y = *(const float4*)&in[i + 4];
    ushort4 o0, o1;
    o0.x = f2bf(x.x); o0.y = f2bf(x.y); o0.z = f2bf(x.z); o0.w = f2bf(x.w);
    o1.x = f2bf(y.x); o1.y = f2bf(y.y); o1.z = f2bf(y.z); o1.w = f2bf(y.w);
    *(ushort4*)&out[i]     = o0;
    *(ushort4*)&out[i + 4] = o1;
}

// ---------------------------------------------------------------------------
// Transpose + convert: WT[n][k] = bf16(W[k][n]), square N=1024
// ---------------------------------------------------------------------------
__global__ __launch_bounds__(256) void transpose_bf16_kernel(
    const float* __restrict__ W, unsigned short* __restrict__ WT)
{
    __shared__ float t[32][33];
    const int c  = threadIdx.x & 31;
    const int r8 = threadIdx.x >> 5;          // 0..7
    const int k0 = blockIdx.y * 32;
    const int n0 = blockIdx.x * 32;
    #pragma unroll
    for (int i = 0; i < 4; ++i) {
        const int r = r8 + i * 8;
        t[r][c] = W[(size_t)(k0 + r) * 1024 + n0 + c];
    }
    __syncthreads();
    #pragma unroll
    for (int i = 0; i < 4; ++i) {
        const int r = r8 + i * 8;
        WT[(size_t)(n0 + r) * 1024 + k0 + c] = f2bf(t[c][r]);
    }
}

// ---------------------------------------------------------------------------
// V transpose: Vp fp32 [B,L,H,HD] -> vtb bf16 [B,H,HD,L]
// ---------------------------------------------------------------------------
__global__ __launch_bounds__(256) void vtrans_kernel(
    const float* __restrict__ Vp, unsigned short* __restrict__ vtb)
{
    __shared__ float t[64][65];
    const int tid = threadIdx.x;
    const int l0  = blockIdx.x * 64;
    const int h   = blockIdx.y;
    const int b   = blockIdx.z;
    const int rr  = tid >> 4;          // 0..15
    const int c4  = (tid & 15) * 4;
    #pragma unroll
    for (int i = 0; i < 4; ++i) {
        const int r = i * 16 + rr;
        const float4 x = *(const float4*)&Vp[((size_t)(b * L_ + l0 + r)) * D_ + h * 64 + c4];
        t[r][c4] = x.x; t[r][c4 + 1] = x.y; t[r][c4 + 2] = x.z; t[r][c4 + 3] = x.w;
    }
    __syncthreads();
    #pragma unroll
    for (int i = 0; i < 4; ++i) {
        const int d = i * 16 + rr;
        ushort4 o;
        o.x = f2bf(t[c4 + 0][d]); o.y = f2bf(t[c4 + 1][d]);
        o.z = f2bf(t[c4 + 2][d]); o.w = f2bf(t[c4 + 3][d]);
        *(ushort4*)&vtb[((size_t)((b * H_ + h) * 64 + d)) * L_ + l0 + c4] = o;
    }
}

// ---------------------------------------------------------------------------
// Pack mask -> key-tile-major bitmask:
// mbt[((b*32 + kt)*2048 + q)*2 + w] covers keys kt*64 + w*32 .. +31
// ---------------------------------------------------------------------------
__global__ __launch_bounds__(256) void pack_mask_t_kernel(
    const int* __restrict__ mask, unsigned int* __restrict__ mbt)
{
    const unsigned g = blockIdx.x * 256 + threadIdx.x;
    const int v = mask[g];
    const unsigned long long bm = __ballot(v != 0);
    const int lane = threadIdx.x & 63;
    const int b = g >> 22;
    const int q = (g >> 11) & 2047;
    const int k = g & 2047;
    const unsigned idx = ((unsigned)(b * 32 + (k >> 6)) * 2048 + q) * 2 + ((k >> 5) & 1);
    if (lane == 0)       mbt[idx] = (unsigned)bm;
    else if (lane == 32) mbt[idx] = (unsigned)(bm >> 32);
}

// ---------------------------------------------------------------------------
// bf16 MFMA GEMM (m97 recipe): C[M,N] = A[M,K] @ WT[N,K]^T + bias[N]
// ---------------------------------------------------------------------------
__global__ __launch_bounds__(256) void gemm_mfma_kernel(
    const unsigned short* __restrict__ A, const unsigned short* __restrict__ WT,
    const float* __restrict__ bias, float* __restrict__ C,
    int M, int N, int K)
{
    __shared__ __align__(16) unsigned short At[128 * 64];
    __shared__ __align__(16) unsigned short Bt[128 * 64];

    const int tid  = threadIdx.x;
    const int lane = tid & 63;
    const int wave = tid >> 6;
    const int wm   = wave >> 1;
    const int wn   = wave & 1;
    const int quad = lane >> 4;
    const int l15  = lane & 15;
    const int m0   = blockIdx.y * 128;
    const int n0   = blockIdx.x * 128;

    f32x4 acc[4][4];
    #pragma unroll
    for (int i = 0; i < 4; ++i)
        #pragma unroll
        for (int j = 0; j < 4; ++j) acc[i][j] = (f32x4)0.f;

    for (int k0 = 0; k0 < K; k0 += 64) {
        __syncthreads();
        #pragma unroll
        for (int i = 0; i < 4; ++i) {
            const int fb  = i * 256 + wave * 64;
            const int f   = fb + lane;
            const int row = f >> 3;
            const int c8  = f & 7;
            async_copy16(&A [(size_t)(m0 + row) * K + k0 + c8 * 8],
                         (char*)At + (size_t)fb * 16);
            async_copy16(&WT[(size_t)(n0 + row) * K + k0 + c8 * 8],
                         (char*)Bt + (size_t)fb * 16);
        }
        __syncthreads();

        #pragma unroll
        for (int kk = 0; kk < 64; kk += 32) {
            short8 afr[4], bfr[4];
            #pragma unroll
            for (int mt = 0; mt < 4; ++mt)
                afr[mt] = *(const short8*)&At[(size_t)(wm * 64 + mt * 16 + l15) * 64 + kk + quad * 8];
            #pragma unroll
            for (int nt = 0; nt < 4; ++nt)
                bfr[nt] = *(const short8*)&Bt[(size_t)(wn * 64 + nt * 16 + l15) * 64 + kk + quad * 8];
            #pragma unroll
            for (int mt = 0; mt < 4; ++mt)
                #pragma unroll
                for (int nt = 0; nt < 4; ++nt)
                    acc[mt][nt] = __builtin_amdgcn_mfma_f32_16x16x32_bf16(
                        afr[mt], bfr[nt], acc[mt][nt], 0, 0, 0);
        }
    }

    #pragma unroll
    for (int nt = 0; nt < 4; ++nt) {
        const int col = n0 + wn * 64 + nt * 16 + l15;
        const float bv = bias[col];
        #pragma unroll
        for (int mt = 0; mt < 4; ++mt) {
            const int r0 = m0 + wm * 64 + mt * 16 + quad * 4;
            #pragma unroll
            for (int r = 0; r < 4; ++r)
                C[(size_t)(r0 + r) * N + col] = acc[mt][nt][r] + bv;
        }
    }
}

// ---------------------------------------------------------------------------
// MFMA flash attention, transposed orientation.
// Block = 256 thr (4 waves), 128 queries/block (32/wave), 64-key tiles.
// S^T = K·Q^T  (C/D: col=query=lane&15, row=key=quad*4+reg)
// ctx^T = V^T·P^T (A=V^T[d][key] from LDS, B=P^T from Pt[q][key] LDS)
// Per-query softmax state is per-lane; key-reduce = in-lane + shfl_xor(16,32).
// Inputs: Qb,Kb bf16 [B,L,D]; Vtg bf16 [B,H,HD,L]; mbt tiled mask bits.
// Output: Cb bf16 [B,L,D].
// ---------------------------------------------------------------------------
#define AQ 128
#define AK 64
#define PSTR 72   // Pt row stride (bf16): 144B = 16B-aligned, 2-way banks only

__global__ __launch_bounds__(256) void attn_mfma_kernel(
    const unsigned short* __restrict__ Qb,
    const unsigned short* __restrict__ Kb,
    const unsigned short* __restrict__ Vtg,
    const unsigned int* __restrict__ mbt,
    unsigned short* __restrict__ Cb)
{
    __shared__ __align__(16) unsigned short Kt[AK * 64];        // [key][d] 8KB
    __shared__ __align__(16) unsigned short Vs[64 * AK];        // [d][key] 8KB
    __shared__ __align__(16) unsigned short Pt[AQ * PSTR];      // [q][key] 18KB
    __shared__ __align__(16) unsigned long long Mt[AQ];         // 1KB

    const int tid  = threadIdx.x;
    const int lane = tid & 63;
    const int w    = tid >> 6;          // wave 0..3: queries w*32..+31
    const int quad = lane >> 4;
    const int l15  = lane & 15;
    const int q0   = blockIdx.x * AQ;
    const int h    = blockIdx.y;
    const int b    = blockIdx.z;

    const float scale = 0.125f * 1.44269504088896340736f;  // exp2 domain

    // Q fragments (B-operand): [qc][kc], resident in VGPRs
    short8 qf[2][2];
    #pragma unroll
    for (int qc = 0; qc < 2; ++qc)
        #pragma unroll
        for (int kc = 0; kc < 2; ++kc)
            qf[qc][kc] = *(const short8*)
                &Qb[((size_t)(b * L_ + q0 + w * 32 + qc * 16 + l15)) * D_
                    + h * 64 + kc * 32 + quad * 8];

    f32x4 ot[4][2];                     // ctx^T acc: [d-tile][q-tile]
    #pragma unroll
    for (int dr = 0; dr < 4; ++dr)
        #pragma unroll
        for (int qc = 0; qc < 2; ++qc) ot[dr][qc] = (f32x4)0.f;
    float m_run[2] = {-INFINITY, -INFINITY};
    float l_run[2] = {0.f, 0.f};

    for (int kt = 0; kt < L_ / AK; ++kt) {
        const int k0 = kt * AK;
        __syncthreads();   // previous tile's LDS (Kt/Vs/Pt/Mt) reads complete
        // stage K tile [64 key][64 d] and V^T tile [64 d][64 key]
        #pragma unroll
        for (int i = 0; i < 2; ++i) {
            const int fb = i * 256 + w * 64;
            const int f  = fb + lane;
            const int r  = f >> 3;
            const int c8 = f & 7;
            async_copy16(&Kb[((size_t)(b * L_ + k0 + r)) * D_ + h * 64 + c8 * 8],
                         (char*)Kt + fb * 16);
            async_copy16(&Vtg[((size_t)((b * H_ + h) * 64 + r)) * L_ + k0 + c8 * 8],
                         (char*)Vs + fb * 16);
        }
        if (w == 3)   // mask tile: 128 q x 64 keys = 1KB contiguous
            async_copy16((const char*)mbt + ((size_t)(b * 32 + kt) * L_ + q0) * 8
                             + lane * 16,
                         (char*)Mt);
        __syncthreads();   // drains vmcnt: tiles ready

        // ---- S^T = K·Q^T : st[key-tile][q-tile] -------------------------
        f32x4 st[4][2];
        #pragma unroll
        for (int kr = 0; kr < 4; ++kr)
            #pragma unroll
            for (int qc = 0; qc < 2; ++qc) st[kr][qc] = (f32x4)0.f;
        #pragma unroll
        for (int kc = 0; kc < 2; ++kc) {
            short8 kf[4];
            #pragma unroll
            for (int kr = 0; kr < 4; ++kr)
                kf[kr] = *(const short8*)&Kt[(kr * 16 + l15) * 64 + kc * 32 + quad * 8];
            #pragma unroll
            for (int kr = 0; kr < 4; ++kr)
                #pragma unroll
                for (int qc = 0; qc < 2; ++qc)
                    st[kr][qc] = __builtin_amdgcn_mfma_f32_16x16x32_bf16(
                        kf[kr], qf[qc][kc], st[kr][qc], 0, 0, 0);
        }

        // ---- online softmax (per-lane per query) + P write --------------
        #pragma unroll
        for (int qc = 0; qc < 2; ++qc) {
            const unsigned long long mrow = Mt[w * 32 + qc * 16 + l15];
            float rmax = -INFINITY;
            #pragma unroll
            for (int kr = 0; kr < 4; ++kr) {
                const unsigned nib = (unsigned)(mrow >> (kr * 16 + quad * 4)) & 0xFu;
                #pragma unroll
                for (int r = 0; r < 4; ++r) {
                    const float x = ((nib >> r) & 1u) ? st[kr][qc][r] * scale
                                                      : -INFINITY;
                    st[kr][qc][r] = x;
                    rmax = fmaxf(rmax, x);
                }
            }
            rmax = fmaxf(rmax, __shfl_xor(rmax, 16));
            rmax = fmaxf(rmax, __shfl_xor(rmax, 32));
            const float mnew  = fmaxf(m_run[qc], rmax);
            const float msafe = fmaxf(mnew, -1e30f);
            const float alpha = exp2f(m_run[qc] - msafe);
            float psum = 0.f;
            #pragma unroll
            for (int kr = 0; kr < 4; ++kr) {
                const float p0 = exp2f(st[kr][qc][0] - msafe);
                const float p1 = exp2f(st[kr][qc][1] - msafe);
                const float p2 = exp2f(st[kr][qc][2] - msafe);
                const float p3 = exp2f(st[kr][qc][3] - msafe);
                psum += (p0 + p1) + (p2 + p3);
                ushort4 pk;
                pk.x = f2bf(p0); pk.y = f2bf(p1); pk.z = f2bf(p2); pk.w = f2bf(p3);
                *(ushort4*)&Pt[(w * 32 + qc * 16 + l15) * PSTR + kr * 16 + quad * 4] = pk;
            }
            psum += __shfl_xor(psum, 16);
            psum += __shfl_xor(psum, 32);
            l_run[qc] = l_run[qc] * alpha + psum;
            m_run[qc] = mnew;
            #pragma unroll
            for (int dr = 0; dr < 4; ++dr) {
                ot[dr][qc][0] *= alpha; ot[dr][qc][1] *= alpha;
                ot[dr][qc][2] *= alpha; ot[dr][qc][3] *= alpha;
            }
        }

        // ---- ctx^T += V^T · P^T  (Pt is wave-private; no barrier needed) -
        #pragma unroll
        for (int kc = 0; kc < 2; ++kc) {
            short8 vf[4], pf[2];
            #pragma unroll
            for (int dr = 0; dr < 4; ++dr)
                vf[dr] = *(const short8*)&Vs[(dr * 16 + l15) * 64 + kc * 32 + quad * 8];
            #pragma unroll
            for (int qc = 0; qc < 2; ++qc)
                pf[qc] = *(const short8*)&Pt[(w * 32 + qc * 16 + l15) * PSTR
                                             + kc * 32 + quad * 8];
            #pragma unroll
            for (int dr = 0; dr < 4; ++dr)
                #pragma unroll
                for (int qc = 0; qc < 2; ++qc)
                    ot[dr][qc] = __builtin_amdgcn_mfma_f32_16x16x32_bf16(
                        vf[dr], pf[qc], ot[dr][qc], 0, 0, 0);
        }
    }

    // ---- epilogue: normalize, store ctx as bf16 [B,L,D] -----------------
    #pragma unroll
    for (int qc = 0; qc < 2; ++qc) {
        const float rinv = (l_run[qc] > 0.f) ? (1.f / l_run[qc]) : 0.f;
        const size_t base = ((size_t)(b * L_ + q0 + w * 32 + qc * 16 + l15)) * D_
                            + h * 64;
        #pragma unroll
        for (int dr = 0; dr < 4; ++dr) {
            ushort4 o;
            o.x = f2bf(ot[dr][qc][0] * rinv);
            o.y = f2bf(ot[dr][qc][1] * rinv);
            o.z = f2bf(ot[dr][qc][2] * rinv);
            o.w = f2bf(ot[dr][qc][3] * rinv);
            *(ushort4*)&Cb[base + dr * 16 + quad * 4] = o;
        }
    }
}

// ---------------------------------------------------------------------------
extern "C" void kernel_launch(void* const* d_in, const int* in_sizes, int n_in,
                              void* d_out, int out_size, void* d_ws, size_t ws_size,
                              hipStream_t stream)
{
    const float* q    = (const float*)d_in[0];
    const float* k    = (const float*)d_in[1];
    const float* v    = (const float*)d_in[2];
    const int*   mask = (const int*)d_in[3];
    const float* WQ   = (const float*)d_in[4];
    const float* bQ   = (const float*)d_in[5];
    const float* WK   = (const float*)d_in[6];
    const float* bK   = (const float*)d_in[7];
    const float* WV   = (const float*)d_in[8];
    const float* bV   = (const float*)d_in[9];
    const float* WO   = (const float*)d_in[10];
    const float* bO   = (const float*)d_in[11];
    float* out = (float*)d_out;

    const size_t NTOK = (size_t)B_ * L_;        // 8192

    // ws map (>=128 MiB proven): fp32 Qp/Kp/Vp + bf16 zones
    char* W = (char*)d_ws;
    float* Qp = (float*)(W);                     // 32 MB
    float* Kp = (float*)(W + ((size_t)32 << 20)); // 32 MB
    float* Vp = (float*)(W + ((size_t)64 << 20)); // 32 MB
    unsigned short* qb  = (unsigned short*)(W + ((size_t)96  << 20)); // 16MB; later qbf
    unsigned short* vb  = (unsigned short*)(W + ((size_t)112 << 20)); // 16MB; later vtb
    unsigned short* cb  = (unsigned short*)(W);                       // Qp zone post-attn
    unsigned short* WTo = (unsigned short*)(W + ((size_t)32 << 20));  // Kp zone post-cvt

    // d_out as scratch until final GEMM:
    unsigned int*   mbt = (unsigned int*)d_out;                              // 2MB
    unsigned short* WTq = (unsigned short*)((char*)d_out + ((size_t)2 << 20));
    unsigned short* WTk = (unsigned short*)((char*)d_out + ((size_t)4 << 20));
    unsigned short* WTv = (unsigned short*)((char*)d_out + ((size_t)6 << 20));
    unsigned short* kb  = (unsigned short*)((char*)d_out + ((size_t)8 << 20)); // 16MB; later kbf

    pack_mask_t_kernel<<<(B_ * L_ * L_) / 256, 256, 0, stream>>>(mask, mbt);

    const int cvtg = (int)(NTOK * D_ / (256 * 8));   // 4096
    cvt_bf16_kernel<<<cvtg, 256, 0, stream>>>(q, qb);
    cvt_bf16_kernel<<<cvtg, 256, 0, stream>>>(k, kb);
    cvt_bf16_kernel<<<cvtg, 256, 0, stream>>>(v, vb);

    dim3 tg(32, 32);
    transpose_bf16_kernel<<<tg, 256, 0, stream>>>(WQ, WTq);
    transpose_bf16_kernel<<<tg, 256, 0, stream>>>(WK, WTk);
    transpose_bf16_kernel<<<tg, 256, 0, stream>>>(WV, WTv);

    dim3 ggrd(D_ / 128, NTOK / 128);            // (8, 64)
    gemm_mfma_kernel<<<ggrd, 256, 0, stream>>>(qb, WTq, bQ, Qp, (int)NTOK, D_, D_);
    gemm_mfma_kernel<<<ggrd, 256, 0, stream>>>(kb, WTk, bK, Kp, (int)NTOK, D_, D_);
    gemm_mfma_kernel<<<ggrd, 256, 0, stream>>>(vb, WTv, bV, Vp, (int)NTOK, D_, D_);

    // bf16 operands for attention (reuse dead zones)
    cvt_bf16_kernel<<<cvtg, 256, 0, stream>>>(Qp, qb);   // qbf
    cvt_bf16_kernel<<<cvtg, 256, 0, stream>>>(Kp, kb);   // kbf
    vtrans_kernel<<<dim3(L_ / 64, H_, B_), 256, 0, stream>>>(Vp, vb);  // vtb

    dim3 agrd(L_ / AQ, H_, B_);                 // (16, 16, 4)
    attn_mfma_kernel<<<agrd, 256, 0, stream>>>(qb, kb, vb, mbt, cb);

    transpose_bf16_kernel<<<tg, 256, 0, stream>>>(WO, WTo);
    gemm_mfma_kernel<<<ggrd, 256, 0, stream>>>(cb, WTo, bO, out, (int)NTOK, D_, D_);
}